// Round 12
// baseline (22.370 us; speedup 1.0000x reference)
//
#include <hip/hip_runtime.h>

#define IMG_H 720
#define IMG_W 1280
#define HW (IMG_H * IMG_W)

#define TXP 64             // pair-columns (x positions) per tile
#define TYR 8              // rows per tile
#define NBX (IMG_W / TXP)  // 20
#define NBY (IMG_H / TYR)  // 90
#define NBLK (NBX * NBY)   // 1800 blocks; each block does BOTH images
#define LW2 74             // f2 stride: 592B row pitch (16B-aligned, bank-spread)
#define LH (TYR + 6)       // 14

// k = sqrt(50*log2(e)); w = exp2(-((k*v - k*c)^2 + r2*S2SCALE))
#define KSCALE 8.493218148592486f
#define INVK   0.11774100235949044f
#define S2SCALE 0.028853900817779268f  // 1/(50*ln2)

typedef float f2 __attribute__((ext_vector_type(2)));

#if defined(__has_builtin)
#if __has_builtin(__builtin_amdgcn_exp2f)
#define EXP2(x) __builtin_amdgcn_exp2f(x)
#else
#define EXP2(x) exp2f(x)
#endif
#if __has_builtin(__builtin_amdgcn_rcpf)
#define RCP(x) __builtin_amdgcn_rcpf(x)
#else
#define RCP(x) (1.0f / (x))
#endif
#else
#define EXP2(x) exp2f(x)
#define RCP(x) (1.0f / (x))
#endif

// spatial sums ry2+rx2 ∈ {0,1,2,4,5,8,9,10,13,18} -> index 0..9
__device__ constexpr int MIDX[19] = {0, 1, 2, -1, 3, 4, -1, -1, 5, 6,
                                     7, -1, -1, 8, -1, -1, -1, -1, 9};

// One packed tap = this (dy,dx) tap for BOTH images of one pixel.
// Native v2f32 ops -> ISel emits v_pk_add_f32/v_pk_fma_f32 with correct
// op_sel (R9/R10 lesson: never hand-encode VOP3P modifier defaults).
__device__ __forceinline__ void tap(f2 v, f2 nck, f2 s2p, f2& aw, f2& aiw) {
    f2 dd = v + nck;                               // v - ck
    f2 e = __builtin_elementwise_fma(dd, dd, s2p); // dd^2 + s2 (positive)
    f2 w;
    w.x = EXP2(-e.x);   // neg folds into v_exp_f32 src modifier
    w.y = EXP2(-e.y);
    aw += w;
    aiw = __builtin_elementwise_fma(w, v, aiw);
}

template <int RY2>
__device__ __forceinline__ void do_row4(const f2* __restrict__ rowptr,
                                        const f2 (&nck)[4], f2 (&aw)[4],
                                        f2 (&aiw)[4], const f2 (&s2)[10]) {
    f2 f[10];
    *(float4*)(&f[0]) = *(const float4*)(rowptr + 0);
    *(float4*)(&f[2]) = *(const float4*)(rowptr + 2);
    *(float4*)(&f[4]) = *(const float4*)(rowptr + 4);
    *(float4*)(&f[6]) = *(const float4*)(rowptr + 6);
    *(float4*)(&f[8]) = *(const float4*)(rowptr + 8);
#pragma unroll
    for (int dx = 0; dx < 7; ++dx) {
        const int sidx = MIDX[RY2 + (dx - 3) * (dx - 3)];  // compile-time
#pragma unroll
        for (int j = 0; j < 4; ++j)
            tap(f[dx + j], nck[j], s2[sidx], aw[j], aiw[j]);
    }
}

__global__ __launch_bounds__(128, 8) void bilateral_pk4(
    const float* __restrict__ I, float* __restrict__ O) {
    int b = blockIdx.x;
    int bx = b % NBX, by = b / NBX;
    int tx0 = bx * TXP, ty0 = by * TYR;
    int tid = threadIdx.x;

    __shared__ f2 S[LH][LW2];
    const float* img0 = I;
    const float* img1 = I + HW;

    // ---- stage both images, interleaved {img0,img1} per f2, k-pre-scaled ----
    bool interior = (bx >= 1) && (bx <= NBX - 2) && (by >= 1) && (by <= NBY - 2);
    if (interior) {
        // 14 rows x 18 chunks of 4 f2-cols = 252 chunks; no clamping needed:
        // bx>=1 -> gx >= 61; bx<=18 -> max gx+3 = 1152+65+3 = 1220 < 1280.
#pragma unroll
        for (int i = 0; i < 2; ++i) {
            int id = tid + i * 128;
            if (id < LH * 18) {
                int r = id / 18, q = id % 18;
                int gy = ty0 - 3 + r, gx = tx0 - 3 + q * 4;
                float4 a0 = *(const float4*)(img0 + gy * IMG_W + gx);
                float4 a1 = *(const float4*)(img1 + gy * IMG_W + gx);
                float4 w0, w1;
                w0.x = a0.x * KSCALE; w0.y = a1.x * KSCALE;
                w0.z = a0.y * KSCALE; w0.w = a1.y * KSCALE;
                w1.x = a0.z * KSCALE; w1.y = a1.z * KSCALE;
                w1.z = a0.w * KSCALE; w1.w = a1.w * KSCALE;
                *(float4*)(&S[r][q * 4]) = w0;
                *(float4*)(&S[r][q * 4 + 2]) = w1;
            }
        }
    } else {
#pragma unroll
        for (int i = 0; i < 9; ++i) {
            int idx = tid + i * 128;
            if (idx < LH * LW2) {
                int r = idx / LW2, c = idx % LW2;
                if (c < 70) {
                    int gy = ty0 - 3 + r, gx = tx0 - 3 + c;
                    float v0 = 0.f, v1 = 0.f;
                    if (gy >= 0 && gy < IMG_H && gx >= 0 && gx < IMG_W) {
                        v0 = img0[gy * IMG_W + gx];
                        v1 = img1[gy * IMG_W + gx];
                    }
                    f2 t = {v0 * KSCALE, v1 * KSCALE};
                    S[r][c] = t;
                }
            }
        }
    }
    __syncthreads();

    // ---- spatial-constant pairs (compile-time indexed; compiler hoists) ----
    const float sv[10] = {0.f, 1.f, 2.f, 4.f, 5.f, 8.f, 9.f, 10.f, 13.f, 18.f};
    f2 s2c[10];
#pragma unroll
    for (int j = 0; j < 10; ++j) {
        float s = sv[j] * S2SCALE;
        s2c[j].x = s;
        s2c[j].y = s;
    }

    // ---- compute: 4 adjacent pixel-pairs (8 outputs) per thread ----
    // py-major lane order: 16-lane b128 groups span 8 rows x 2 px -> all 32
    // banks covered exactly 2x (2-way = free, m136).
    int py = tid & 7;
    int px = tid >> 3;   // 0..15
    int x0 = px * 4;     // f2 units

    f2 aw[4] = {{0.f, 0.f}, {0.f, 0.f}, {0.f, 0.f}, {0.f, 0.f}};
    f2 aiw[4] = {{0.f, 0.f}, {0.f, 0.f}, {0.f, 0.f}, {0.f, 0.f}};
    f2 nck[4];

    // Row 3 first: centers come from this row's registers.
    {
        const f2* rowptr = &S[py + 3][x0];
        f2 f[10];
        *(float4*)(&f[0]) = *(const float4*)(rowptr + 0);
        *(float4*)(&f[2]) = *(const float4*)(rowptr + 2);
        *(float4*)(&f[4]) = *(const float4*)(rowptr + 4);
        *(float4*)(&f[6]) = *(const float4*)(rowptr + 6);
        *(float4*)(&f[8]) = *(const float4*)(rowptr + 8);
#pragma unroll
        for (int j = 0; j < 4; ++j) nck[j] = -f[3 + j];
#pragma unroll
        for (int dx = 0; dx < 7; ++dx) {
            const int sidx = MIDX[(dx - 3) * (dx - 3)];
#pragma unroll
            for (int j = 0; j < 4; ++j)
                tap(f[dx + j], nck[j], s2c[sidx], aw[j], aiw[j]);
        }
    }
    do_row4<9>(&S[py + 0][x0], nck, aw, aiw, s2c);
    do_row4<4>(&S[py + 1][x0], nck, aw, aiw, s2c);
    do_row4<1>(&S[py + 2][x0], nck, aw, aiw, s2c);
    do_row4<1>(&S[py + 4][x0], nck, aw, aiw, s2c);
    do_row4<4>(&S[py + 5][x0], nck, aw, aiw, s2c);
    do_row4<9>(&S[py + 6][x0], nck, aw, aiw, s2c);

    int oy = ty0 + py;
    float4 r0, r1;
    r0.x = aiw[0].x * RCP(aw[0].x) * INVK;
    r0.y = aiw[1].x * RCP(aw[1].x) * INVK;
    r0.z = aiw[2].x * RCP(aw[2].x) * INVK;
    r0.w = aiw[3].x * RCP(aw[3].x) * INVK;
    r1.x = aiw[0].y * RCP(aw[0].y) * INVK;
    r1.y = aiw[1].y * RCP(aw[1].y) * INVK;
    r1.z = aiw[2].y * RCP(aw[2].y) * INVK;
    r1.w = aiw[3].y * RCP(aw[3].y) * INVK;
    *(float4*)(O + (size_t)oy * IMG_W + tx0 + x0) = r0;
    *(float4*)(O + HW + (size_t)oy * IMG_W + tx0 + x0) = r1;
}

extern "C" void kernel_launch(void* const* d_in, const int* in_sizes, int n_in,
                              void* d_out, int out_size, void* d_ws, size_t ws_size,
                              hipStream_t stream) {
    const float* I = (const float*)d_in[0];
    float* O = (float*)d_out;
    bilateral_pk4<<<NBLK, 128, 0, stream>>>(I, O);
}